// Round 1
// baseline (337.584 us; speedup 1.0000x reference)
//
#include <hip/hip_runtime.h>

// Problem constants (from reference): B=8, F=256, T=512, D=40, S=4
#define BATCHES 8
#define NROWS (256 * 512)        // N = F*T = 131072
#define DE 40                    // embedding dim
#define SV 4                     // assignment dim
#define CC 44                    // concatenated cols (E: 0..39, V: 40..43)
#define CPAD 48                  // LDS row pitch (floats)
#define GSZ (CC * CC)            // 1936 Gram entries per batch
#define ROWS_PER_BLOCK 1024
#define CHUNKS (NROWS / ROWS_PER_BLOCK)   // 128 chunks per batch
#define RSTAGE 32
#define NSTAGES (ROWS_PER_BLOCK / RSTAGE) // 32

// Kernel 1: accumulate per-batch 44x44 Gram G = [E|V]^T [E|V] into d_ws via atomics.
// Block = 256 threads; threads 0..241 each own a 2x4 tile of G (22 x 11 tiles = 44x44).
__global__ __launch_bounds__(256) void gram_kernel(const float* __restrict__ E,
                                                   const float* __restrict__ V,
                                                   float* __restrict__ G) {
    __shared__ float rows[RSTAGE][CPAD];

    const int b = blockIdx.x / CHUNKS;
    const int chunk = blockIdx.x % CHUNKS;
    const long row0 = (long)chunk * ROWS_PER_BLOCK;

    // Per-batch bases; rows are contiguous so chunks are contiguous float4 streams.
    const float4* __restrict__ Eg = (const float4*)(E + (size_t)b * NROWS * DE);
    const float4* __restrict__ Vg = (const float4*)(V + (size_t)b * NROWS * SV);

    const int tid = threadIdx.x;
    const int ti = tid / 11;   // 0..21 -> Gram rows 2*ti, 2*ti+1
    const int tj = tid % 11;   // 0..10 -> Gram cols 4*tj .. 4*tj+3
    const bool active = (tid < 242);

    float acc[2][4] = {{0.f, 0.f, 0.f, 0.f}, {0.f, 0.f, 0.f, 0.f}};

    for (int s = 0; s < NSTAGES; ++s) {
        const long r0 = row0 + (long)s * RSTAGE;
        __syncthreads();   // previous stage's reads done before overwrite

        // Stage E: 32 rows * 10 float4 = 320 coalesced float4 loads.
        for (int idx = tid; idx < RSTAGE * 10; idx += 256) {
            const int r = idx / 10, c4 = idx % 10;
            float4 v = Eg[(r0 + r) * 10 + c4];
            *(float4*)&rows[r][c4 * 4] = v;
        }
        // Stage V: 32 rows * 1 float4, placed at cols 40..43.
        if (tid < RSTAGE) {
            float4 v = Vg[r0 + tid];
            *(float4*)&rows[tid][40] = v;
        }
        __syncthreads();

        if (active) {
            #pragma unroll 8
            for (int r = 0; r < RSTAGE; ++r) {
                const float a0 = rows[r][2 * ti];
                const float a1 = rows[r][2 * ti + 1];
                const float4 bb = *(const float4*)&rows[r][4 * tj];
                acc[0][0] += a0 * bb.x; acc[0][1] += a0 * bb.y;
                acc[0][2] += a0 * bb.z; acc[0][3] += a0 * bb.w;
                acc[1][0] += a1 * bb.x; acc[1][1] += a1 * bb.y;
                acc[1][2] += a1 * bb.z; acc[1][3] += a1 * bb.w;
            }
        }
    }

    if (active) {
        float* Gb = G + (size_t)b * GSZ;
        #pragma unroll
        for (int a = 0; a < 2; ++a) {
            #pragma unroll
            for (int c = 0; c < 4; ++c) {
                atomicAdd(&Gb[(2 * ti + a) * CC + (4 * tj + c)], acc[a][c]);
            }
        }
    }
}

// Kernel 2: out = sum_b sum_ij sign(i,j) * G[b][i][j]^2 / (B*N)
// sign = +1 if (i<40)==(j<40) (EE or VV block), else -1 (mixed blocks).
__global__ __launch_bounds__(256) void finish_kernel(const float* __restrict__ G,
                                                     float* __restrict__ out) {
    const int tid = threadIdx.x;
    float sum = 0.f;
    for (int idx = tid; idx < BATCHES * GSZ; idx += 256) {
        const int ij = idx % GSZ;
        const int i = ij / CC;
        const int j = ij % CC;
        const float g = G[idx];
        const float sgn = ((i < DE) == (j < DE)) ? 1.f : -1.f;
        sum += sgn * g * g;
    }
    // wave64 reduce
    #pragma unroll
    for (int o = 32; o > 0; o >>= 1) sum += __shfl_down(sum, o, 64);
    __shared__ float ws[4];
    if ((tid & 63) == 0) ws[tid >> 6] = sum;
    __syncthreads();
    if (tid == 0) {
        const float t = ws[0] + ws[1] + ws[2] + ws[3];
        out[0] = t / (float)((size_t)BATCHES * NROWS);
    }
}

extern "C" void kernel_launch(void* const* d_in, const int* in_sizes, int n_in,
                              void* d_out, int out_size, void* d_ws, size_t ws_size,
                              hipStream_t stream) {
    const float* E = (const float*)d_in[0];   // embeddings (B,F,T,D) fp32
    const float* V = (const float*)d_in[1];   // assignments (B,F,T,S) fp32
    float* G = (float*)d_ws;                  // B * 44*44 fp32 Gram accumulators

    hipMemsetAsync(G, 0, (size_t)BATCHES * GSZ * sizeof(float), stream);
    gram_kernel<<<BATCHES * CHUNKS, 256, 0, stream>>>(E, V, G);
    finish_kernel<<<1, 256, 0, stream>>>(G, (float*)d_out);
}